// Round 1
// baseline (646.701 us; speedup 1.0000x reference)
//
#include <hip/hip_runtime.h>
#include <math.h>

#define N_VEC 65536
#define D 64
#define K 1024
#define VQ_EPS 1e-10f

// ---------------------------------------------------------------------------
// Kernel A: per-code squared norms  enorm[k] = sum_j e[k][j]^2
// ---------------------------------------------------------------------------
__global__ void enorm_kernel(const float* __restrict__ emb,
                             float* __restrict__ enorm) {
    int k = blockIdx.x * blockDim.x + threadIdx.x;
    if (k < K) {
        const float4* e4 = reinterpret_cast<const float4*>(emb + (size_t)k * D);
        float s = 0.f;
#pragma unroll
        for (int j = 0; j < D / 4; ++j) {
            float4 v = e4[j];
            s += v.x * v.x + v.y * v.y + v.z * v.z + v.w * v.w;
        }
        enorm[k] = s;
    }
}

// ---------------------------------------------------------------------------
// Kernel B: one thread per input vector. x[64] in VGPRs; loop codes (uniform
// address -> s_load path), 4 codes per iteration for ILP (grid is only
// 256 blocks = ~1 wave/SIMD, so the FMA dep-chain must be broken in-thread).
// dist = ||e||^2 - 2 x.e  (row-constant ||x||^2 omitted; argmin unchanged).
// Strict < in ascending k == jnp.argmin first-occurrence tie-break.
// ---------------------------------------------------------------------------
__global__ void __launch_bounds__(256)
vq_kernel(const float* __restrict__ x,
          const float* __restrict__ emb,
          const float* __restrict__ enorm,
          float* __restrict__ out,
          int* __restrict__ counts) {
    int v = blockIdx.x * blockDim.x + threadIdx.x;
    const float* xp = x + (size_t)v * D;

    float xv[D];
#pragma unroll
    for (int j = 0; j < D / 4; ++j) {
        float4 t = reinterpret_cast<const float4*>(xp)[j];
        xv[4 * j + 0] = t.x;
        xv[4 * j + 1] = t.y;
        xv[4 * j + 2] = t.z;
        xv[4 * j + 3] = t.w;
    }

    float best = 3.4e38f;
    int bestk = 0;

    for (int k = 0; k < K; k += 4) {
        const float* e0 = emb + (size_t)k * D;
        float d0 = 0.f, d1 = 0.f, d2 = 0.f, d3 = 0.f;
#pragma unroll
        for (int j = 0; j < D; ++j) {
            float xj = xv[j];
            d0 = fmaf(xj, e0[j], d0);
            d1 = fmaf(xj, e0[D + j], d1);
            d2 = fmaf(xj, e0[2 * D + j], d2);
            d3 = fmaf(xj, e0[3 * D + j], d3);
        }
        float q0 = enorm[k + 0] - 2.f * d0;
        float q1 = enorm[k + 1] - 2.f * d1;
        float q2 = enorm[k + 2] - 2.f * d2;
        float q3 = enorm[k + 3] - 2.f * d3;
        if (q0 < best) { best = q0; bestk = k + 0; }
        if (q1 < best) { best = q1; bestk = k + 1; }
        if (q2 < best) { best = q2; bestk = k + 2; }
        if (q3 < best) { best = q3; bestk = k + 3; }
    }

    // quantized = embeddings[bestk]
    const float4* eq = reinterpret_cast<const float4*>(emb + (size_t)bestk * D);
    float4* op = reinterpret_cast<float4*>(out + (size_t)v * D);
#pragma unroll
    for (int j = 0; j < D / 4; ++j) op[j] = eq[j];

    atomicAdd(counts + bestk, 1);
}

// ---------------------------------------------------------------------------
// Kernel C: perplexity = exp(-sum p log(p+eps)), p = counts/N.
// One block of 1024 threads, LDS tree reduction.
// ---------------------------------------------------------------------------
__global__ void perplexity_kernel(const int* __restrict__ counts,
                                  float* __restrict__ outp) {
    __shared__ float sdata[1024];
    int t = threadIdx.x;
    float p = (float)counts[t] * (1.0f / (float)N_VEC);
    sdata[t] = p * logf(p + VQ_EPS);
    __syncthreads();
    for (int s = 512; s > 0; s >>= 1) {
        if (t < s) sdata[t] += sdata[t + s];
        __syncthreads();
    }
    if (t == 0) *outp = expf(-sdata[0]);
}

// ---------------------------------------------------------------------------
extern "C" void kernel_launch(void* const* d_in, const int* in_sizes, int n_in,
                              void* d_out, int out_size, void* d_ws, size_t ws_size,
                              hipStream_t stream) {
    const float* x   = (const float*)d_in[0];   // 2*32*32*32*64 fp32
    const float* emb = (const float*)d_in[1];   // 1024*64 fp32
    float* out = (float*)d_out;                 // 4194304 quantized + 1 perplexity

    float* enorm = (float*)d_ws;                          // K floats
    int*   counts = (int*)((char*)d_ws + K * sizeof(float)); // K ints

    hipMemsetAsync(counts, 0, K * sizeof(int), stream);

    enorm_kernel<<<K / 256, 256, 0, stream>>>(emb, enorm);
    vq_kernel<<<N_VEC / 256, 256, 0, stream>>>(x, emb, enorm, out, counts);
    perplexity_kernel<<<1, 1024, 0, stream>>>(counts, out + (size_t)N_VEC * D);
}

// Round 2
// 197.098 us; speedup vs baseline: 3.2811x; 3.2811x over previous
//
#include <hip/hip_runtime.h>
#include <math.h>

#define N_VEC 65536
#define D 64
#define K 1024
#define VQ_EPS 1e-10f

// ---------------------------------------------------------------------------
// Kernel A: enorm[k] = ||e_k||^2, and zero the counts buffer (replaces memset)
// ---------------------------------------------------------------------------
__global__ void enorm_kernel(const float* __restrict__ emb,
                             float* __restrict__ enorm,
                             int* __restrict__ counts) {
    int k = blockIdx.x * 256 + threadIdx.x;
    const float4* e4 = reinterpret_cast<const float4*>(emb + (size_t)k * D);
    float s = 0.f;
#pragma unroll
    for (int j = 0; j < D / 4; ++j) {
        float4 v = e4[j];
        s += v.x * v.x + v.y * v.y + v.z * v.z + v.w * v.w;
    }
    enorm[k] = s;
    counts[k] = 0;
}

// ---------------------------------------------------------------------------
// Kernel B: LDS-tiled register-blocked distance/argmin.
// Block = 256 threads, 64 vectors x all 1024 codes (16 code-tiles of 64).
// xs/es stored transposed [j][vec]/[j][code] so the microkernel reads are
// float4 ds_read_b128 (2-way bank aliasing = free on gfx950).
// Each thread: 4 vectors x 4 codes outer product, fp32 accumulate.
// dist = ||e||^2 - 2 x.e (row-constant ||x||^2 dropped; argmin unchanged).
// Tie-break: ascending code order + strict <, and index-priority in the
// cross-lane reduction == jnp.argmin first-occurrence.
// ---------------------------------------------------------------------------
__global__ void __launch_bounds__(256, 4)
vq_kernel(const float* __restrict__ x,
          const float* __restrict__ emb,
          const float* __restrict__ enorm,
          float* __restrict__ out,
          int* __restrict__ counts) {
    __shared__ float xs[D][64];   // xs[j][vec]   16 KB
    __shared__ float es[D][64];   // es[j][code]  16 KB
    __shared__ float en[K];       // all code norms 4 KB
    __shared__ int   bk[64];      // per-vector best code

    const int t      = threadIdx.x;
    const int lane_v = t & 63;    // staging: which row (vec or code)
    const int jq     = t >> 6;    // staging: which j-quad group
    const int tx     = t & 15;    // compute: code group (4 codes)
    const int ty     = t >> 4;    // compute: vector group (4 vectors)
    const int vb     = blockIdx.x * 64;

    // stage x-tile (transposed) — once per block
#pragma unroll
    for (int pass = 0; pass < 4; ++pass) {
        int j = pass * 16 + jq * 4;
        float4 v = *reinterpret_cast<const float4*>(x + (size_t)(vb + lane_v) * D + j);
        xs[j + 0][lane_v] = v.x;
        xs[j + 1][lane_v] = v.y;
        xs[j + 2][lane_v] = v.z;
        xs[j + 3][lane_v] = v.w;
    }
    // stage all 1024 enorms
    reinterpret_cast<float4*>(en)[t] = reinterpret_cast<const float4*>(enorm)[t];

    float best[4] = {3.4e38f, 3.4e38f, 3.4e38f, 3.4e38f};
    int   bestk[4] = {0, 0, 0, 0};

    for (int ct = 0; ct < 16; ++ct) {
        const int cb = ct * 64;
        __syncthreads();   // protects es reuse AND first-iteration staging
#pragma unroll
        for (int pass = 0; pass < 4; ++pass) {
            int j = pass * 16 + jq * 4;
            float4 v = *reinterpret_cast<const float4*>(emb + (size_t)(cb + lane_v) * D + j);
            es[j + 0][lane_v] = v.x;
            es[j + 1][lane_v] = v.y;
            es[j + 2][lane_v] = v.z;
            es[j + 3][lane_v] = v.w;
        }
        __syncthreads();

        float acc[4][4];
#pragma unroll
        for (int a = 0; a < 4; ++a)
#pragma unroll
            for (int b = 0; b < 4; ++b) acc[a][b] = 0.f;

#pragma unroll 8
        for (int j = 0; j < D; ++j) {
            float4 xa = *reinterpret_cast<const float4*>(&xs[j][ty * 4]);
            float4 eb = *reinterpret_cast<const float4*>(&es[j][tx * 4]);
            acc[0][0] = fmaf(xa.x, eb.x, acc[0][0]);
            acc[0][1] = fmaf(xa.x, eb.y, acc[0][1]);
            acc[0][2] = fmaf(xa.x, eb.z, acc[0][2]);
            acc[0][3] = fmaf(xa.x, eb.w, acc[0][3]);
            acc[1][0] = fmaf(xa.y, eb.x, acc[1][0]);
            acc[1][1] = fmaf(xa.y, eb.y, acc[1][1]);
            acc[1][2] = fmaf(xa.y, eb.z, acc[1][2]);
            acc[1][3] = fmaf(xa.y, eb.w, acc[1][3]);
            acc[2][0] = fmaf(xa.z, eb.x, acc[2][0]);
            acc[2][1] = fmaf(xa.z, eb.y, acc[2][1]);
            acc[2][2] = fmaf(xa.z, eb.z, acc[2][2]);
            acc[2][3] = fmaf(xa.z, eb.w, acc[2][3]);
            acc[3][0] = fmaf(xa.w, eb.x, acc[3][0]);
            acc[3][1] = fmaf(xa.w, eb.y, acc[3][1]);
            acc[3][2] = fmaf(xa.w, eb.z, acc[3][2]);
            acc[3][3] = fmaf(xa.w, eb.w, acc[3][3]);
        }

        // distances + best update (codes ascending -> first-occurrence ties)
#pragma unroll
        for (int c = 0; c < 4; ++c) {
            const int code = cb + tx * 4 + c;
            const float q = en[code];
#pragma unroll
            for (int v = 0; v < 4; ++v) {
                float dist = fmaf(-2.f, acc[v][c], q);
                if (dist < best[v]) { best[v] = dist; bestk[v] = code; }
            }
        }
    }

    // reduce across the 16 code-lanes (same ty group) — index-priority ties
#pragma unroll
    for (int m = 1; m <= 8; m <<= 1) {
#pragma unroll
        for (int v = 0; v < 4; ++v) {
            float ob = __shfl_xor(best[v], m, 64);
            int   ok = __shfl_xor(bestk[v], m, 64);
            if (ob < best[v] || (ob == best[v] && ok < bestk[v])) {
                best[v] = ob; bestk[v] = ok;
            }
        }
    }
    if (tx == 0) {
#pragma unroll
        for (int v = 0; v < 4; ++v) {
            bk[ty * 4 + v] = bestk[v];
            atomicAdd(&counts[bestk[v]], 1);
        }
    }
    __syncthreads();

    // gather embedding rows -> out, coalesced (4 threads per vector row)
    const int vec = t >> 2, part = t & 3;
    const int kk = bk[vec];
#pragma unroll
    for (int i = 0; i < 4; ++i) {
        float4 ev = *reinterpret_cast<const float4*>(emb + (size_t)kk * D + part * 16 + i * 4);
        *reinterpret_cast<float4*>(out + (size_t)(vb + vec) * D + part * 16 + i * 4) = ev;
    }
}

// ---------------------------------------------------------------------------
// Kernel C: perplexity = exp(-sum p log(p+eps)), p = counts/N. 256 threads.
// ---------------------------------------------------------------------------
__global__ void perplexity_kernel(const int* __restrict__ counts,
                                  float* __restrict__ outp) {
    int t = threadIdx.x;
    float s = 0.f;
#pragma unroll
    for (int i = 0; i < 4; ++i) {
        float p = (float)counts[t + i * 256] * (1.0f / (float)N_VEC);
        s += p * logf(p + VQ_EPS);
    }
#pragma unroll
    for (int m = 1; m < 64; m <<= 1) s += __shfl_xor(s, m, 64);
    __shared__ float ws[4];
    if ((t & 63) == 0) ws[t >> 6] = s;
    __syncthreads();
    if (t == 0) *outp = expf(-(ws[0] + ws[1] + ws[2] + ws[3]));
}

// ---------------------------------------------------------------------------
extern "C" void kernel_launch(void* const* d_in, const int* in_sizes, int n_in,
                              void* d_out, int out_size, void* d_ws, size_t ws_size,
                              hipStream_t stream) {
    const float* x   = (const float*)d_in[0];   // [65536, 64] fp32
    const float* emb = (const float*)d_in[1];   // [1024, 64] fp32
    float* out = (float*)d_out;                 // 4194304 quantized + 1 perplexity

    float* enorm  = (float*)d_ws;
    int*   counts = (int*)((char*)d_ws + K * sizeof(float));

    enorm_kernel<<<K / 256, 256, 0, stream>>>(emb, enorm, counts);
    vq_kernel<<<N_VEC / 64, 256, 0, stream>>>(x, emb, enorm, out, counts);
    perplexity_kernel<<<1, 256, 0, stream>>>(counts, out + (size_t)N_VEC * D);
}